// Round 13
// baseline (541.865 us; speedup 1.0000x reference)
//
#include <hip/hip_runtime.h>
#include <hip/hip_bf16.h>
#include <hip/hip_runtime_api.h>

// Problem constants
#define NROWS 8192
#define HID 128
#define OUTC 40

typedef unsigned short ushort_t;
typedef __attribute__((ext_vector_type(8))) short bf16x8;
typedef __attribute__((ext_vector_type(4))) short short4v;
typedef __attribute__((ext_vector_type(4))) float f32x4;

// f32 -> bf16 RNE
__device__ __forceinline__ short f2bf(float f) {
    unsigned int u = __float_as_uint(f);
    unsigned int r = (u + 0x7FFFu + ((u >> 16) & 1u)) >> 16;
    return (short)r;
}
__device__ __forceinline__ float bf2f(ushort_t b) {
    return __uint_as_float(((unsigned int)b) << 16);
}
__device__ __forceinline__ float exp2_fast(float x) {
#if __has_builtin(__builtin_amdgcn_exp2f)
    return __builtin_amdgcn_exp2f(x);
#else
    return exp2f(x);
#endif
}
// bias (log2 domain) with fixed softmax max M=16 folded in:
//   r = scale2/d - 16 ; d==0 (inf) or overflow -> -16.
// Scores s = bias + qk bounded above -> exp2(s) never overflows; softmax is
// shift-invariant -> identical result; split-K partials merge by plain sum.
__device__ __forceinline__ float bias_of16(float f, float scale2) {
    float r = scale2 * __builtin_amdgcn_rcpf(f);
    bool bad = (__float_as_uint(r) & 0x7F800000u) == 0x7F800000u;
    return bad ? -16.f : r - 16.f;
}

// Generic A-fragment tile layout over [rows][128 cols]:
//   frag[rt=row/16][kf=col/32][quad=(col%32)/8][l15=row%16][j=col%8]
// -> a wave's load for (rt,kf): base + ((rt*4+kf)*4+quad)*128 + l15*8 : 1KB contiguous.

// ---------- K0: one-time f32 -> frag-ordered bf16 (x + all weights) ----------
__global__ __launch_bounds__(256) void k_prep(const float* __restrict__ x,
                                              const float* __restrict__ Wi,
                                              const float* __restrict__ Wp,
                                              const float* __restrict__ Wo,
                                              const float* __restrict__ Wout,
                                              ushort_t* __restrict__ xfr,
                                              ushort_t* __restrict__ wifr,
                                              ushort_t* __restrict__ wpfr,
                                              ushort_t* __restrict__ wofr,
                                              ushort_t* __restrict__ woutfr) {
    int rb = blockIdx.x;
    const float* src; ushort_t* dst; int rt; int nrows;
    if (rb < 512)      { src = x;    dst = xfr;    rt = rb;       nrows = 1 << 30; }
    else if (rb < 520) { src = Wi;   dst = wifr;   rt = rb - 512; nrows = 1 << 30; }
    else if (rb < 544) { src = Wp;   dst = wpfr;   rt = rb - 520; nrows = 1 << 30; }
    else if (rb < 552) { src = Wo;   dst = wofr;   rt = rb - 544; nrows = 1 << 30; }
    else               { src = Wout; dst = woutfr; rt = rb - 552; nrows = OUTC; }  // pad to 48 rows
    int t = threadIdx.x;
    int r = t >> 4, c8 = t & 15;
    int row = rt * 16 + r;
    float4 a = {0.f, 0.f, 0.f, 0.f}, b = {0.f, 0.f, 0.f, 0.f};
    if (row < nrows) {
        a = *(const float4*)(src + (size_t)row * 128 + c8 * 8);
        b = *(const float4*)(src + (size_t)row * 128 + c8 * 8 + 4);
    }
    short4v s0 = {f2bf(a.x), f2bf(a.y), f2bf(a.z), f2bf(a.w)};
    short4v s1 = {f2bf(b.x), f2bf(b.y), f2bf(b.z), f2bf(b.w)};
    ushort_t* d = dst + ((((size_t)rt * 4 + (c8 >> 2)) * 4 + (c8 & 3)) * 16 + r) * 8;
    *(short4v*)d = s0;
    *(short4v*)(d + 4) = s1;
}

// ---------- K1: fused h = x@Wi^T+bi -> qkv = h@Wp^T+bp (frag-ordered in/out) ----------
__global__ __launch_bounds__(256) void k_qkv_fused(const ushort_t* __restrict__ xfr,
                                                   const ushort_t* __restrict__ wifr,
                                                   const float* __restrict__ bi,
                                                   const ushort_t* __restrict__ wpfr,
                                                   const float* __restrict__ bp,
                                                   ushort_t* __restrict__ hbf,
                                                   ushort_t* __restrict__ qfr,
                                                   ushort_t* __restrict__ kfr,
                                                   ushort_t* __restrict__ vfr) {
    __shared__ __align__(16) ushort_t h_s[16][136];
    const int w = threadIdx.x >> 6, lane = threadIdx.x & 63;
    const int l15 = lane & 15, quad = lane >> 4;
    const int rt = blockIdx.x;
    const int r0 = rt * 16;

    // phase 1: 16 token rows; wave w owns output cols w*32..+31
    {
        bf16x8 af[4], bfr[2][4];
#pragma unroll
        for (int kf = 0; kf < 4; ++kf)
            af[kf] = *(const bf16x8*)(xfr + (((size_t)rt * 4 + kf) * 4 + quad) * 128 + l15 * 8);
#pragma unroll
        for (int nt = 0; nt < 2; ++nt)
#pragma unroll
            for (int kf = 0; kf < 4; ++kf)
                bfr[nt][kf] = *(const bf16x8*)(wifr + (((size_t)(w * 2 + nt) * 4 + kf) * 4 + quad) * 128 + l15 * 8);
#pragma unroll
        for (int nt = 0; nt < 2; ++nt) {
            float bias = bi[w * 32 + nt * 16 + l15];
            f32x4 c = {bias, bias, bias, bias};
#pragma unroll
            for (int kf = 0; kf < 4; ++kf)
                c = __builtin_amdgcn_mfma_f32_16x16x32_bf16(af[kf], bfr[nt][kf], c, 0, 0, 0);
            int col = w * 32 + nt * 16 + l15;
#pragma unroll
            for (int r = 0; r < 4; ++r) {
                int row = quad * 4 + r;
                short hv = f2bf(c[r]);
                h_s[row][col] = (ushort_t)hv;
                hbf[(size_t)(r0 + row) * 128 + col] = (ushort_t)hv;
            }
        }
    }
    __syncthreads();
    // phase 2: qkv; wave w owns output cols w*96..+95
    bf16x8 af2[4];
#pragma unroll
    for (int kf = 0; kf < 4; ++kf)
        af2[kf] = *(const bf16x8*)&h_s[l15][kf * 32 + quad * 8];
    const float QS = 0.25503482459918643f;  // log2e / sqrt(32)
#pragma unroll
    for (int nt = 0; nt < 6; ++nt) {
        const int n0 = w * 96 + nt * 16;
        bf16x8 bfr[4];
#pragma unroll
        for (int kf = 0; kf < 4; ++kf)
            bfr[kf] = *(const bf16x8*)(wpfr + (((size_t)(w * 6 + nt) * 4 + kf) * 4 + quad) * 128 + l15 * 8);
        float bias = bp[n0 + l15];
        f32x4 c = {bias, bias, bias, bias};
#pragma unroll
        for (int kf = 0; kf < 4; ++kf)
            c = __builtin_amdgcn_mfma_f32_16x16x32_bf16(af2[kf], bfr[kf], c, 0, 0, 0);
        if (n0 < 256) {  // Q or K -> generic frag order over [token][128]
            int col = (n0 < 128) ? (n0 + l15) : (n0 - 128 + l15);
            ushort_t* dstf = (n0 < 128) ? qfr : kfr;
            float sc = (n0 < 128) ? QS : 1.0f;
            int hh = col >> 5, qd = (col >> 3) & 3, j = col & 7;
#pragma unroll
            for (int r = 0; r < 4; ++r) {
                int token = r0 + quad * 4 + r;
                dstf[((((size_t)(token >> 4) * 4 + hh) * 4 + qd) * 16 + (token & 15)) * 8 + j] =
                    (ushort_t)f2bf(c[r] * sc);
            }
        } else {  // V -> B-operand frag order (keys along j), short4v store
            int d = n0 - 256 + l15;
            int hh = d >> 5, dt = (d >> 4) & 1, dl = d & 15;
            int key0 = r0 + quad * 4;
            int kb = key0 >> 5, qk = (key0 >> 3) & 3, j0 = key0 & 7;
            short4v pk = {f2bf(c[0]), f2bf(c[1]), f2bf(c[2]), f2bf(c[3])};
            *(short4v*)&vfr[(((((size_t)kb * 4 + hh) * 2 + dt) * 4 + qk) * 16 + dl) * 8 + j0] = pk;
        }
    }
}

// ---------- K2: flash attention partials (fixed-max softmax) ----------
// Wave = (32 q, head, quarter-K). Grid 1024 = 256 qt x 4 quarters.
// P transposed C-layout -> B-operand layout via ds_bpermute (in-register; NO p_s
// LDS, no lgkmcnt serialization) -> LDS = bias only 33.3 KB -> 3-4 blocks/CU
// (51.7 KB only co-scheduled 2 — measured R12). Bias staged in ROUNDS of 4 tiles
// (32x256 f32 super-tile, 1KB/row contiguous NT fetch), 2 barriers per 4 iters.
__global__ __launch_bounds__(256, 2) void k_attn(const ushort_t* __restrict__ qfr,
                                                 const ushort_t* __restrict__ kfr,
                                                 const ushort_t* __restrict__ vfr,
                                                 const float* __restrict__ sp,
                                                 const float* __restrict__ scale_p,
                                                 ushort_t* __restrict__ pob,
                                                 float* __restrict__ pml) {
    __shared__ __align__(16) float bias_s[32][260];  // 33.3 KB (only LDS)

    const int t = threadIdx.x;
    const int h = t >> 6;  // wave = head
    const int lane = t & 63, l15 = lane & 15, quad = lane >> 4;
    const int qt = blockIdx.x & 255;
    const int quarter = blockIdx.x >> 8;
    const int q0 = qt * 32;
    const int k0 = quarter * 2048;
    const float scale2 = scale_p[0] * 1.4426950408889634f;  // log2e folded

    // bias staging role: thread t covers sp row q0+(t>>3), col lanes (t&7)*4 (+32k)
    const int brow = t >> 3, bcol = (t & 7) * 4;
    const float* spb = sp + (size_t)(q0 + brow) * NROWS + k0 + bcol;

    // loop-invariant Q^T fragments (pre-scaled)
    bf16x8 bq[2];
#pragma unroll
    for (int qq = 0; qq < 2; ++qq)
        bq[qq] = *(const bf16x8*)(qfr + ((((size_t)(q0 >> 4) + qq) * 4 + h) * 4 + quad) * 128 + l15 * 8);

    // K/V fragment pipeline (1 tile ahead)
    bf16x8 af[4], vf[2][2];
#pragma unroll
    for (int c = 0; c < 4; ++c)
        af[c] = *(const bf16x8*)(kfr + ((((size_t)(k0 >> 4) + c) * 4 + h) * 4 + quad) * 128 + l15 * 8);
#pragma unroll
    for (int dt = 0; dt < 2; ++dt)
#pragma unroll
        for (int kc = 0; kc < 2; ++kc)
            vf[dt][kc] = *(const bf16x8*)(vfr + (((((size_t)(k0 >> 5) + kc) * 4 + h) * 2 + dt) * 4 + quad) * 128 + l15 * 8);

    // round 0 prologue: fetch + stage
    f32x4 breg[8];
#pragma unroll
    for (int k = 0; k < 8; ++k)
        breg[k] = __builtin_nontemporal_load((const f32x4*)(spb + k * 32));
#pragma unroll
    for (int k = 0; k < 8; ++k) {
        f32x4 cv = {bias_of16(breg[k][0], scale2), bias_of16(breg[k][1], scale2),
                    bias_of16(breg[k][2], scale2), bias_of16(breg[k][3], scale2)};
        *(f32x4*)&bias_s[brow][k * 32 + bcol] = cv;
    }
    __syncthreads();

    f32x4 oacc[2][2] = {};
    float l[2] = {0.f, 0.f};
    const int sl0 = ((lane & 16) << 1) + l15;  // 32*(quad&1) + l15

    for (int rnd = 0; rnd < 8; ++rnd) {
        // fetch next round's 32x256 super-tile (1KB/row contiguous, NT)
        if (rnd < 7) {
#pragma unroll
            for (int k = 0; k < 8; ++k)
                breg[k] = __builtin_nontemporal_load((const f32x4*)(spb + (rnd + 1) * 256 + k * 32));
        }
#pragma unroll
        for (int j = 0; j < 4; ++j) {
            const int it = rnd * 4 + j;
            // C-init from staged (bias - 16)
            f32x4 sacc[4][2];
#pragma unroll
            for (int c = 0; c < 4; ++c)
#pragma unroll
                for (int qq = 0; qq < 2; ++qq)
                    sacc[c][qq] = *(const f32x4*)&bias_s[qq * 16 + l15][j * 64 + c * 16 + quad * 4];
            // QK^T (log2-domain scores, pre-shifted by -16)
#pragma unroll
            for (int c = 0; c < 4; ++c)
#pragma unroll
                for (int qq = 0; qq < 2; ++qq)
                    sacc[c][qq] = __builtin_amdgcn_mfma_f32_16x16x32_bf16(af[c], bq[qq], sacc[c][qq], 0, 0, 0);
            // prefetch next K fragments
            if (it < 31) {
                size_t rtk = (size_t)(k0 >> 4) + (it + 1) * 4;
#pragma unroll
                for (int c = 0; c < 4; ++c)
                    af[c] = *(const bf16x8*)(kfr + (((rtk + c) * 4 + h) * 4 + quad) * 128 + l15 * 8);
            }
            // p = exp2(s); accumulate l per-lane; pack + cross-lane transpose + PV
#pragma unroll
            for (int qq = 0; qq < 2; ++qq) {
                float lsum = 0.f;
#pragma unroll
                for (int c = 0; c < 4; ++c)
#pragma unroll
                    for (int r = 0; r < 4; ++r) {
                        float p = exp2_fast(sacc[c][qq][r]);
                        sacc[c][qq][r] = p;
                        lsum += p;
                    }
                l[qq] += lsum;
                // pack to bf16 pairs: pk[c][p] = keys (c*16+quad*4+2p, +2p+1)
                unsigned pk[4][2];
#pragma unroll
                for (int c = 0; c < 4; ++c) {
                    unsigned b0 = __float_as_uint(sacc[c][qq][0]);
                    unsigned b1 = __float_as_uint(sacc[c][qq][1]);
                    unsigned b2 = __float_as_uint(sacc[c][qq][2]);
                    unsigned b3 = __float_as_uint(sacc[c][qq][3]);
                    pk[c][0] = __builtin_amdgcn_perm(b1, b0, 0x07060302);
                    pk[c][1] = __builtin_amdgcn_perm(b3, b2, 0x07060302);
                }
                // transpose to B-operand layout: B[kc] elem j = key kc*32+quad*8+j,
                // source lane 32*(quad&1)+16*(u>>1)+l15, reg pk[kc*2+(quad>>1)][u&1]
                union { unsigned u[4]; bf16x8 v; } pf[2];
#pragma unroll
                for (int kc = 0; kc < 2; ++kc)
#pragma unroll
                    for (int u = 0; u < 4; ++u) {
                        int sl = sl0 + ((u >> 1) << 4);
                        unsigned x0 = (unsigned)__shfl((int)pk[kc * 2][u & 1], sl, 64);
                        unsigned x1 = (unsigned)__shfl((int)pk[kc * 2 + 1][u & 1], sl, 64);
                        pf[kc].u[u] = (quad & 2) ? x1 : x0;
                    }
                // PV: O^T += V^T . P^T
#pragma unroll
                for (int dt = 0; dt < 2; ++dt) {
                    oacc[dt][qq] = __builtin_amdgcn_mfma_f32_16x16x32_bf16(vf[dt][0], pf[0].v, oacc[dt][qq], 0, 0, 0);
                    oacc[dt][qq] = __builtin_amdgcn_mfma_f32_16x16x32_bf16(vf[dt][1], pf[1].v, oacc[dt][qq], 0, 0, 0);
                }
            }
            // prefetch next V fragments
            if (it < 31) {
                size_t kb = (size_t)(k0 >> 5) + (it + 1) * 2;
#pragma unroll
                for (int dt = 0; dt < 2; ++dt)
#pragma unroll
                    for (int kc = 0; kc < 2; ++kc)
                        vf[dt][kc] = *(const bf16x8*)(vfr + ((((kb + kc) * 4 + h) * 2 + dt) * 4 + quad) * 128 + l15 * 8);
            }
        }
        // stage next round from regs (single buffer: barrier, overwrite, barrier)
        if (rnd < 7) {
            __syncthreads();
#pragma unroll
            for (int k = 0; k < 8; ++k) {
                f32x4 cv = {bias_of16(breg[k][0], scale2), bias_of16(breg[k][1], scale2),
                            bias_of16(breg[k][2], scale2), bias_of16(breg[k][3], scale2)};
                *(f32x4*)&bias_s[brow][k * 32 + bcol] = cv;
            }
            __syncthreads();
        }
    }

    // epilogue: reduce l across quads; store partials
    // pob layout: [qtile][h][quarter][dt][quad][l15][4] -> lane 8B, wave 512B contig
#pragma unroll
    for (int qq = 0; qq < 2; ++qq) {
        float lt = l[qq];
        lt += __shfl_xor(lt, 16, 64);
        lt += __shfl_xor(lt, 32, 64);
        int qtile = qt * 2 + qq;
        if (quad == 0)
            pml[((size_t)(q0 + qq * 16 + l15) * 4 + h) * 4 + quarter] = lt;
#pragma unroll
        for (int dt = 0; dt < 2; ++dt) {
            short4v pk = {f2bf(oacc[dt][qq][0]), f2bf(oacc[dt][qq][1]),
                          f2bf(oacc[dt][qq][2]), f2bf(oacc[dt][qq][3])};
            *(short4v*)&pob[(((((size_t)qtile * 4 + h) * 4 + quarter) * 2 + dt) * 256)
                            + quad * 64 + l15 * 4] = pk;
        }
    }
}

// ---------- K3: epilogue (4-way partial merge + out_proj -> relu+residual -> W_out -> log_softmax) ----------
__global__ __launch_bounds__(256) void k_epi(const ushort_t* __restrict__ hbf,
                                             const ushort_t* __restrict__ pob,
                                             const float* __restrict__ pml,
                                             const ushort_t* __restrict__ wofr,
                                             const float* __restrict__ bo,
                                             const ushort_t* __restrict__ woutfr,
                                             const float* __restrict__ bout,
                                             float* __restrict__ out) {
    __shared__ __align__(16) ushort_t hr_s[16][136];
    const int w = threadIdx.x >> 6, lane = threadIdx.x & 63;
    const int l15 = lane & 15, quad = lane >> 4;
    const int rt = blockIdx.x;
    const int r0 = rt * 16;

    // phase A: merge 4 quarter-partials (plain sum; fixed-max softmax) -> A-frags;
    // o2 = O @ Wo^T + bo -> relu -> +h -> hr_s (bf16)
    {
        bf16x8 af[4], bfr[2][4];
#pragma unroll
        for (int kf = 0; kf < 4; ++kf) {
            float4 lv = *(const float4*)(pml + ((size_t)(r0 + l15) * 4 + kf) * 4);
            float linv = 1.f / (lv.x + lv.y + lv.z + lv.w);
            float acc[8] = {0.f, 0.f, 0.f, 0.f, 0.f, 0.f, 0.f, 0.f};
#pragma unroll
            for (int j = 0; j < 4; ++j) {
                size_t base = ((((size_t)rt * 4 + kf) * 4 + j) * 2 + (quad >> 1)) * 256
                              + (quad & 1) * 128 + l15 * 4;
                short4v v0 = *(const short4v*)(pob + base);
                short4v v1 = *(const short4v*)(pob + base + 64);
#pragma unroll
                for (int e = 0; e < 4; ++e) {
                    acc[e] += bf2f((ushort_t)v0[e]);
                    acc[4 + e] += bf2f((ushort_t)v1[e]);
                }
            }
            bf16x8 a;
#pragma unroll
            for (int e = 0; e < 8; ++e) a[e] = f2bf(acc[e] * linv);
            af[kf] = a;
        }
#pragma unroll
        for (int nt = 0; nt < 2; ++nt)
#pragma unroll
            for (int kf = 0; kf < 4; ++kf)
                bfr[nt][kf] = *(const bf16x8*)(wofr + (((size_t)(w * 2 + nt) * 4 + kf) * 4 + quad) * 128 + l15 * 8);
#pragma unroll
        for (int nt = 0; nt < 2; ++nt) {
            float bias = bo[w * 32 + nt * 16 + l15];
            f32x4 c = {bias, bias, bias, bias};
#pragma unroll
            for (int kf = 0; kf < 4; ++kf)
                c = __builtin_amdgcn_mfma_f32_16x16x32_bf16(af[kf], bfr[nt][kf], c, 0, 0, 0);
            int col = w * 32 + nt * 16 + l15;
#pragma unroll
            for (int r = 0; r < 4; ++r) {
                int row = quad * 4 + r;
                float val = fmaxf(c[r], 0.f) + bf2f(hbf[(size_t)(r0 + row) * 128 + col]);
                hr_s[row][col] = (ushort_t)f2bf(val);
            }
        }
    }
    __syncthreads();
    // phase B (wave 0): logits^T = Wout . hr^T ; in-lane log_softmax per row
    if (w == 0) {
        f32x4 c[3];
#pragma unroll
        for (int mt = 0; mt < 3; ++mt)
#pragma unroll
            for (int r = 0; r < 4; ++r) {
                int oc = mt * 16 + quad * 4 + r;
                c[mt][r] = (oc < OUTC) ? bout[oc] : 0.f;
            }
#pragma unroll
        for (int kf = 0; kf < 4; ++kf) {
            bf16x8 bfrag = *(const bf16x8*)&hr_s[l15][kf * 32 + quad * 8];
#pragma unroll
            for (int mt = 0; mt < 3; ++mt) {
                bf16x8 afr = *(const bf16x8*)(woutfr + (((size_t)mt * 4 + kf) * 4 + quad) * 128 + l15 * 8);
                c[mt] = __builtin_amdgcn_mfma_f32_16x16x32_bf16(afr, bfrag, c[mt], 0, 0, 0);
            }
        }
        float mx = -1e30f;
#pragma unroll
        for (int mt = 0; mt < 3; ++mt)
#pragma unroll
            for (int r = 0; r < 4; ++r) {
                int oc = mt * 16 + quad * 4 + r;
                if (oc >= OUTC) c[mt][r] = -1e30f;
                mx = fmaxf(mx, c[mt][r]);
            }
        mx = fmaxf(mx, __shfl_xor(mx, 16, 64));
        mx = fmaxf(mx, __shfl_xor(mx, 32, 64));
        float ssum = 0.f;
#pragma unroll
        for (int mt = 0; mt < 3; ++mt)
#pragma unroll
            for (int r = 0; r < 4; ++r) ssum += __expf(c[mt][r] - mx);
        ssum += __shfl_xor(ssum, 16, 64);
        ssum += __shfl_xor(ssum, 32, 64);
        float lse = __logf(ssum) + mx;
        int row = r0 + l15;
#pragma unroll
        for (int mt = 0; mt < 2; ++mt) {
            float4 st = make_float4(c[mt][0] - lse, c[mt][1] - lse, c[mt][2] - lse, c[mt][3] - lse);
            *(float4*)(out + (size_t)row * OUTC + mt * 16 + quad * 4) = st;
        }
        if (quad < 2) {
            float4 st = make_float4(c[2][0] - lse, c[2][1] - lse, c[2][2] - lse, c[2][3] - lse);
            *(float4*)(out + (size_t)row * OUTC + 32 + quad * 4) = st;
        }
    }
}

extern "C" void kernel_launch(void* const* d_in, const int* in_sizes, int n_in,
                              void* d_out, int out_size, void* d_ws, size_t ws_size,
                              hipStream_t stream) {
    const float* x          = (const float*)d_in[0];
    // d_in[1] = pos_enc (unused in forward, faithful to reference)
    const float* sp         = (const float*)d_in[2];
    const float* W_in       = (const float*)d_in[3];
    const float* b_in       = (const float*)d_in[4];
    const float* in_proj_w  = (const float*)d_in[5];
    const float* in_proj_b  = (const float*)d_in[6];
    const float* out_proj_w = (const float*)d_in[7];
    const float* out_proj_b = (const float*)d_in[8];
    const float* W_out      = (const float*)d_in[9];
    const float* b_out      = (const float*)d_in[10];
    const float* scale      = (const float*)d_in[11];

    float*    pml    = (float*)d_ws;                           // 8192*16 f32 = 512 KiB
    ushort_t* pob    = (ushort_t*)(pml + (size_t)NROWS * 16);  // 8 MiB bf16 partial O
    ushort_t* xfr    = pob + (size_t)NROWS * 512;
    ushort_t* qfr    = xfr + (size_t)NROWS * 128;
    ushort_t* kfr    = qfr + (size_t)NROWS * 128;
    ushort_t* vfr    = kfr + (size_t)NROWS * 128;
    ushort_t* hbf    = vfr + (size_t)NROWS * 128;
    ushort_t* wifr   = hbf + (size_t)NROWS * 128;
    ushort_t* wpfr   = wifr + 128 * 128;
    ushort_t* wofr   = wpfr + 384 * 128;
    ushort_t* woutfr = wofr + 128 * 128;                       // 48*128 (zero-padded)
    float*    out    = (float*)d_out;

    hipLaunchKernelGGL(k_prep, dim3(555), dim3(256), 0, stream,
                       x, W_in, in_proj_w, out_proj_w, W_out, xfr, wifr, wpfr, wofr, woutfr);
    hipLaunchKernelGGL(k_qkv_fused, dim3(NROWS / 16), dim3(256), 0, stream,
                       xfr, wifr, b_in, wpfr, in_proj_b, hbf, qfr, kfr, vfr);
    hipLaunchKernelGGL(k_attn, dim3(256 * 4), dim3(256), 0, stream,
                       qfr, kfr, vfr, sp, scale, pob, pml);
    hipLaunchKernelGGL(k_epi, dim3(NROWS / 16), dim3(256), 0, stream,
                       hbf, pob, pml, wofr, out_proj_b, woutfr, b_out, out);
}

// Round 14
// 437.212 us; speedup vs baseline: 1.2394x; 1.2394x over previous
//
#include <hip/hip_runtime.h>
#include <hip/hip_bf16.h>
#include <hip/hip_runtime_api.h>

// Problem constants
#define NROWS 8192
#define HID 128
#define OUTC 40

typedef unsigned short ushort_t;
typedef __attribute__((ext_vector_type(8))) short bf16x8;
typedef __attribute__((ext_vector_type(4))) short short4v;
typedef __attribute__((ext_vector_type(4))) float f32x4;

// f32 -> bf16 RNE
__device__ __forceinline__ short f2bf(float f) {
    unsigned int u = __float_as_uint(f);
    unsigned int r = (u + 0x7FFFu + ((u >> 16) & 1u)) >> 16;
    return (short)r;
}
__device__ __forceinline__ float bf2f(ushort_t b) {
    return __uint_as_float(((unsigned int)b) << 16);
}
__device__ __forceinline__ float exp2_fast(float x) {
#if __has_builtin(__builtin_amdgcn_exp2f)
    return __builtin_amdgcn_exp2f(x);
#else
    return exp2f(x);
#endif
}
// bias (log2 domain) with fixed softmax max M=16 folded in:
//   r = scale2/d - 16 ; d==0 (inf) or overflow -> -16.
// Scores s = bias + qk bounded above -> exp2(s) never overflows; softmax is
// shift-invariant -> identical result; split-K partials merge by plain sum.
__device__ __forceinline__ float bias_of16(float f, float scale2) {
    float r = scale2 * __builtin_amdgcn_rcpf(f);
    bool bad = (__float_as_uint(r) & 0x7F800000u) == 0x7F800000u;
    return bad ? -16.f : r - 16.f;
}

// Generic A-fragment tile layout over [rows][128 cols]:
//   frag[rt=row/16][kf=col/32][quad=(col%32)/8][l15=row%16][j=col%8]
// -> a wave's load for (rt,kf): base + ((rt*4+kf)*4+quad)*128 + l15*8 : 1KB contiguous.

// ---------- K0: one-time f32 -> frag-ordered bf16 (x + all weights) ----------
__global__ __launch_bounds__(256) void k_prep(const float* __restrict__ x,
                                              const float* __restrict__ Wi,
                                              const float* __restrict__ Wp,
                                              const float* __restrict__ Wo,
                                              const float* __restrict__ Wout,
                                              ushort_t* __restrict__ xfr,
                                              ushort_t* __restrict__ wifr,
                                              ushort_t* __restrict__ wpfr,
                                              ushort_t* __restrict__ wofr,
                                              ushort_t* __restrict__ woutfr) {
    int rb = blockIdx.x;
    const float* src; ushort_t* dst; int rt; int nrows;
    if (rb < 512)      { src = x;    dst = xfr;    rt = rb;       nrows = 1 << 30; }
    else if (rb < 520) { src = Wi;   dst = wifr;   rt = rb - 512; nrows = 1 << 30; }
    else if (rb < 544) { src = Wp;   dst = wpfr;   rt = rb - 520; nrows = 1 << 30; }
    else if (rb < 552) { src = Wo;   dst = wofr;   rt = rb - 544; nrows = 1 << 30; }
    else               { src = Wout; dst = woutfr; rt = rb - 552; nrows = OUTC; }  // pad to 48 rows
    int t = threadIdx.x;
    int r = t >> 4, c8 = t & 15;
    int row = rt * 16 + r;
    float4 a = {0.f, 0.f, 0.f, 0.f}, b = {0.f, 0.f, 0.f, 0.f};
    if (row < nrows) {
        a = *(const float4*)(src + (size_t)row * 128 + c8 * 8);
        b = *(const float4*)(src + (size_t)row * 128 + c8 * 8 + 4);
    }
    short4v s0 = {f2bf(a.x), f2bf(a.y), f2bf(a.z), f2bf(a.w)};
    short4v s1 = {f2bf(b.x), f2bf(b.y), f2bf(b.z), f2bf(b.w)};
    ushort_t* d = dst + ((((size_t)rt * 4 + (c8 >> 2)) * 4 + (c8 & 3)) * 16 + r) * 8;
    *(short4v*)d = s0;
    *(short4v*)(d + 4) = s1;
}

// ---------- K1: fused h = x@Wi^T+bi -> qkv = h@Wp^T+bp (frag-ordered in/out) ----------
__global__ __launch_bounds__(256) void k_qkv_fused(const ushort_t* __restrict__ xfr,
                                                   const ushort_t* __restrict__ wifr,
                                                   const float* __restrict__ bi,
                                                   const ushort_t* __restrict__ wpfr,
                                                   const float* __restrict__ bp,
                                                   ushort_t* __restrict__ hbf,
                                                   ushort_t* __restrict__ qfr,
                                                   ushort_t* __restrict__ kfr,
                                                   ushort_t* __restrict__ vfr) {
    __shared__ __align__(16) ushort_t h_s[16][136];
    const int w = threadIdx.x >> 6, lane = threadIdx.x & 63;
    const int l15 = lane & 15, quad = lane >> 4;
    const int rt = blockIdx.x;
    const int r0 = rt * 16;

    // phase 1: 16 token rows; wave w owns output cols w*32..+31
    {
        bf16x8 af[4], bfr[2][4];
#pragma unroll
        for (int kf = 0; kf < 4; ++kf)
            af[kf] = *(const bf16x8*)(xfr + (((size_t)rt * 4 + kf) * 4 + quad) * 128 + l15 * 8);
#pragma unroll
        for (int nt = 0; nt < 2; ++nt)
#pragma unroll
            for (int kf = 0; kf < 4; ++kf)
                bfr[nt][kf] = *(const bf16x8*)(wifr + (((size_t)(w * 2 + nt) * 4 + kf) * 4 + quad) * 128 + l15 * 8);
#pragma unroll
        for (int nt = 0; nt < 2; ++nt) {
            float bias = bi[w * 32 + nt * 16 + l15];
            f32x4 c = {bias, bias, bias, bias};
#pragma unroll
            for (int kf = 0; kf < 4; ++kf)
                c = __builtin_amdgcn_mfma_f32_16x16x32_bf16(af[kf], bfr[nt][kf], c, 0, 0, 0);
            int col = w * 32 + nt * 16 + l15;
#pragma unroll
            for (int r = 0; r < 4; ++r) {
                int row = quad * 4 + r;
                short hv = f2bf(c[r]);
                h_s[row][col] = (ushort_t)hv;
                hbf[(size_t)(r0 + row) * 128 + col] = (ushort_t)hv;
            }
        }
    }
    __syncthreads();
    // phase 2: qkv; wave w owns output cols w*96..+95
    bf16x8 af2[4];
#pragma unroll
    for (int kf = 0; kf < 4; ++kf)
        af2[kf] = *(const bf16x8*)&h_s[l15][kf * 32 + quad * 8];
    const float QS = 0.25503482459918643f;  // log2e / sqrt(32)
#pragma unroll
    for (int nt = 0; nt < 6; ++nt) {
        const int n0 = w * 96 + nt * 16;
        bf16x8 bfr[4];
#pragma unroll
        for (int kf = 0; kf < 4; ++kf)
            bfr[kf] = *(const bf16x8*)(wpfr + (((size_t)(w * 6 + nt) * 4 + kf) * 4 + quad) * 128 + l15 * 8);
        float bias = bp[n0 + l15];
        f32x4 c = {bias, bias, bias, bias};
#pragma unroll
        for (int kf = 0; kf < 4; ++kf)
            c = __builtin_amdgcn_mfma_f32_16x16x32_bf16(af2[kf], bfr[kf], c, 0, 0, 0);
        if (n0 < 256) {  // Q or K -> generic frag order over [token][128]
            int col = (n0 < 128) ? (n0 + l15) : (n0 - 128 + l15);
            ushort_t* dstf = (n0 < 128) ? qfr : kfr;
            float sc = (n0 < 128) ? QS : 1.0f;
            int hh = col >> 5, qd = (col >> 3) & 3, j = col & 7;
#pragma unroll
            for (int r = 0; r < 4; ++r) {
                int token = r0 + quad * 4 + r;
                dstf[((((size_t)(token >> 4) * 4 + hh) * 4 + qd) * 16 + (token & 15)) * 8 + j] =
                    (ushort_t)f2bf(c[r] * sc);
            }
        } else {  // V -> B-operand frag order (keys along j), short4v store
            int d = n0 - 256 + l15;
            int hh = d >> 5, dt = (d >> 4) & 1, dl = d & 15;
            int key0 = r0 + quad * 4;
            int kb = key0 >> 5, qk = (key0 >> 3) & 3, j0 = key0 & 7;
            short4v pk = {f2bf(c[0]), f2bf(c[1]), f2bf(c[2]), f2bf(c[3])};
            *(short4v*)&vfr[(((((size_t)kb * 4 + hh) * 2 + dt) * 4 + qk) * 16 + dl) * 8 + j0] = pk;
        }
    }
}

// ---------- K2: flash attention partials (fixed-max softmax) ----------
// Wave = (32 q, head, K-half). Grid 512. Bias staged in ROUNDS of 4 tiles
// (32x256 f32 super-tile, 1KB/row contiguous NT fetch), register-held pipeline,
// 2 barriers per 4 iters. P round-trip is qq-SEQUENTIAL so p_s is single-qq
// (9.2 KB): total LDS 42.5 KB -> crosses the 3-blocks/CU boundary (51.7 KB only
// co-scheduled 2 — measured R12). VGPR 128, no tight launch bound (R11 spill).
__global__ __launch_bounds__(256, 2) void k_attn(const ushort_t* __restrict__ qfr,
                                                 const ushort_t* __restrict__ kfr,
                                                 const ushort_t* __restrict__ vfr,
                                                 const float* __restrict__ sp,
                                                 const float* __restrict__ scale_p,
                                                 ushort_t* __restrict__ pob,
                                                 float* __restrict__ pml) {
    __shared__ __align__(16) float bias_s[32][260];    // 33.3 KB
    __shared__ __align__(16) ushort_t p_s[4][16][72];  // 9.2 KB

    const int t = threadIdx.x;
    const int h = t >> 6;  // wave = head
    const int lane = t & 63, l15 = lane & 15, quad = lane >> 4;
    const int qt = blockIdx.x & 255;
    const int half = blockIdx.x >> 8;
    const int q0 = qt * 32;
    const int k0 = half * 4096;
    const float scale2 = scale_p[0] * 1.4426950408889634f;  // log2e folded

    // bias staging role: thread t covers sp row q0+(t>>3), col lanes (t&7)*4 (+32k)
    const int brow = t >> 3, bcol = (t & 7) * 4;
    const float* spb = sp + (size_t)(q0 + brow) * NROWS + k0 + bcol;

    // loop-invariant Q^T fragments (pre-scaled)
    bf16x8 bq[2];
#pragma unroll
    for (int qq = 0; qq < 2; ++qq)
        bq[qq] = *(const bf16x8*)(qfr + ((((size_t)(q0 >> 4) + qq) * 4 + h) * 4 + quad) * 128 + l15 * 8);

    // K/V fragment pipeline (1 tile ahead)
    bf16x8 af[4], vf[2][2];
#pragma unroll
    for (int c = 0; c < 4; ++c)
        af[c] = *(const bf16x8*)(kfr + ((((size_t)(k0 >> 4) + c) * 4 + h) * 4 + quad) * 128 + l15 * 8);
#pragma unroll
    for (int dt = 0; dt < 2; ++dt)
#pragma unroll
        for (int kc = 0; kc < 2; ++kc)
            vf[dt][kc] = *(const bf16x8*)(vfr + (((((size_t)(k0 >> 5) + kc) * 4 + h) * 2 + dt) * 4 + quad) * 128 + l15 * 8);

    // round 0 prologue: fetch + stage
    f32x4 breg[8];
#pragma unroll
    for (int k = 0; k < 8; ++k)
        breg[k] = __builtin_nontemporal_load((const f32x4*)(spb + k * 32));
#pragma unroll
    for (int k = 0; k < 8; ++k) {
        f32x4 cv = {bias_of16(breg[k][0], scale2), bias_of16(breg[k][1], scale2),
                    bias_of16(breg[k][2], scale2), bias_of16(breg[k][3], scale2)};
        *(f32x4*)&bias_s[brow][k * 32 + bcol] = cv;
    }
    __syncthreads();

    f32x4 oacc[2][2] = {};
    float l[2] = {0.f, 0.f};

    for (int rnd = 0; rnd < 8; ++rnd) {
        // fetch next round's 32x256 super-tile (1KB/row contiguous, NT)
        if (rnd < 7) {
#pragma unroll
            for (int k = 0; k < 8; ++k)
                breg[k] = __builtin_nontemporal_load((const f32x4*)(spb + (rnd + 1) * 256 + k * 32));
        }
#pragma unroll
        for (int j = 0; j < 4; ++j) {
            const int it = rnd * 4 + j;
            // C-init from staged (bias - 16)
            f32x4 sacc[4][2];
#pragma unroll
            for (int c = 0; c < 4; ++c)
#pragma unroll
                for (int qq = 0; qq < 2; ++qq)
                    sacc[c][qq] = *(const f32x4*)&bias_s[qq * 16 + l15][j * 64 + c * 16 + quad * 4];
            // QK^T (log2-domain scores, pre-shifted by -16)
#pragma unroll
            for (int c = 0; c < 4; ++c)
#pragma unroll
                for (int qq = 0; qq < 2; ++qq)
                    sacc[c][qq] = __builtin_amdgcn_mfma_f32_16x16x32_bf16(af[c], bq[qq], sacc[c][qq], 0, 0, 0);
            // prefetch next K fragments
            if (it < 31) {
                size_t rtk = (size_t)(k0 >> 4) + (it + 1) * 4;
#pragma unroll
                for (int c = 0; c < 4; ++c)
                    af[c] = *(const bf16x8*)(kfr + (((rtk + c) * 4 + h) * 4 + quad) * 128 + l15 * 8);
            }
            // per q-tile: p = exp2(s), l accumulate, pack -> p_s (single-qq buffer,
            // reused sequentially; DS in-order per wave makes WAR safe), PV MFMAs
#pragma unroll
            for (int qq = 0; qq < 2; ++qq) {
                float lsum = 0.f;
#pragma unroll
                for (int c = 0; c < 4; ++c)
#pragma unroll
                    for (int r = 0; r < 4; ++r) {
                        float p = exp2_fast(sacc[c][qq][r]);
                        sacc[c][qq][r] = p;
                        lsum += p;
                    }
                l[qq] += lsum;
#pragma unroll
                for (int c = 0; c < 4; ++c) {
                    unsigned b0 = __float_as_uint(sacc[c][qq][0]);
                    unsigned b1 = __float_as_uint(sacc[c][qq][1]);
                    unsigned b2 = __float_as_uint(sacc[c][qq][2]);
                    unsigned b3 = __float_as_uint(sacc[c][qq][3]);
                    uint2 pw;
                    pw.x = __builtin_amdgcn_perm(b1, b0, 0x07060302);
                    pw.y = __builtin_amdgcn_perm(b3, b2, 0x07060302);
                    *(uint2*)&p_s[h][l15][c * 16 + quad * 4] = pw;
                }
                asm volatile("s_waitcnt lgkmcnt(0)" ::: "memory");  // same-wave P RAW
                bf16x8 pf0 = *(const bf16x8*)&p_s[h][l15][quad * 8];
                bf16x8 pf1 = *(const bf16x8*)&p_s[h][l15][32 + quad * 8];
#pragma unroll
                for (int dt = 0; dt < 2; ++dt) {
                    oacc[dt][qq] = __builtin_amdgcn_mfma_f32_16x16x32_bf16(vf[dt][0], pf0, oacc[dt][qq], 0, 0, 0);
                    oacc[dt][qq] = __builtin_amdgcn_mfma_f32_16x16x32_bf16(vf[dt][1], pf1, oacc[dt][qq], 0, 0, 0);
                }
            }
            // prefetch next V fragments
            if (it < 31) {
                size_t kb = (size_t)(k0 >> 5) + (it + 1) * 2;
#pragma unroll
                for (int dt = 0; dt < 2; ++dt)
#pragma unroll
                    for (int kc = 0; kc < 2; ++kc)
                        vf[dt][kc] = *(const bf16x8*)(vfr + ((((kb + kc) * 4 + h) * 2 + dt) * 4 + quad) * 128 + l15 * 8);
            }
        }
        // stage next round from regs (single buffer: barrier, overwrite, barrier)
        if (rnd < 7) {
            __syncthreads();
#pragma unroll
            for (int k = 0; k < 8; ++k) {
                f32x4 cv = {bias_of16(breg[k][0], scale2), bias_of16(breg[k][1], scale2),
                            bias_of16(breg[k][2], scale2), bias_of16(breg[k][3], scale2)};
                *(f32x4*)&bias_s[brow][k * 32 + bcol] = cv;
            }
            __syncthreads();
        }
    }

    // epilogue: reduce l across quads; store partials
    // pob layout: [qtile][h][half][dt][quad][l15][4] -> lane 8B, wave 512B contig
#pragma unroll
    for (int qq = 0; qq < 2; ++qq) {
        float lt = l[qq];
        lt += __shfl_xor(lt, 16, 64);
        lt += __shfl_xor(lt, 32, 64);
        int qtile = qt * 2 + qq;
        if (quad == 0)
            pml[((size_t)(q0 + qq * 16 + l15) * 4 + h) * 2 + half] = lt;
#pragma unroll
        for (int dt = 0; dt < 2; ++dt) {
            short4v pk = {f2bf(oacc[dt][qq][0]), f2bf(oacc[dt][qq][1]),
                          f2bf(oacc[dt][qq][2]), f2bf(oacc[dt][qq][3])};
            *(short4v*)&pob[(((((size_t)qtile * 4 + h) * 2 + half) * 2 + dt) * 256)
                            + quad * 64 + l15 * 4] = pk;
        }
    }
}

// ---------- K3: epilogue (2-way partial merge + out_proj -> relu+residual -> W_out -> log_softmax) ----------
__global__ __launch_bounds__(256) void k_epi(const ushort_t* __restrict__ hbf,
                                             const ushort_t* __restrict__ pob,
                                             const float* __restrict__ pml,
                                             const ushort_t* __restrict__ wofr,
                                             const float* __restrict__ bo,
                                             const ushort_t* __restrict__ woutfr,
                                             const float* __restrict__ bout,
                                             float* __restrict__ out) {
    __shared__ __align__(16) ushort_t hr_s[16][136];
    const int w = threadIdx.x >> 6, lane = threadIdx.x & 63;
    const int l15 = lane & 15, quad = lane >> 4;
    const int rt = blockIdx.x;
    const int r0 = rt * 16;

    // phase A: merge 2 half-partials (plain sum) -> A-frags;
    // o2 = O @ Wo^T + bo -> relu -> +h -> hr_s (bf16)
    {
        bf16x8 af[4], bfr[2][4];
#pragma unroll
        for (int kf = 0; kf < 4; ++kf) {
            float2 lv = *(const float2*)(pml + ((size_t)(r0 + l15) * 4 + kf) * 2);
            float linv = 1.f / (lv.x + lv.y);
            float acc[8] = {0.f, 0.f, 0.f, 0.f, 0.f, 0.f, 0.f, 0.f};
#pragma unroll
            for (int j = 0; j < 2; ++j) {
                size_t base = ((((size_t)rt * 4 + kf) * 2 + j) * 2 + (quad >> 1)) * 256
                              + (quad & 1) * 128 + l15 * 4;
                short4v v0 = *(const short4v*)(pob + base);
                short4v v1 = *(const short4v*)(pob + base + 64);
#pragma unroll
                for (int e = 0; e < 4; ++e) {
                    acc[e] += bf2f((ushort_t)v0[e]);
                    acc[4 + e] += bf2f((ushort_t)v1[e]);
                }
            }
            bf16x8 a;
#pragma unroll
            for (int e = 0; e < 8; ++e) a[e] = f2bf(acc[e] * linv);
            af[kf] = a;
        }
#pragma unroll
        for (int nt = 0; nt < 2; ++nt)
#pragma unroll
            for (int kf = 0; kf < 4; ++kf)
                bfr[nt][kf] = *(const bf16x8*)(wofr + (((size_t)(w * 2 + nt) * 4 + kf) * 4 + quad) * 128 + l15 * 8);
#pragma unroll
        for (int nt = 0; nt < 2; ++nt) {
            float bias = bo[w * 32 + nt * 16 + l15];
            f32x4 c = {bias, bias, bias, bias};
#pragma unroll
            for (int kf = 0; kf < 4; ++kf)
                c = __builtin_amdgcn_mfma_f32_16x16x32_bf16(af[kf], bfr[nt][kf], c, 0, 0, 0);
            int col = w * 32 + nt * 16 + l15;
#pragma unroll
            for (int r = 0; r < 4; ++r) {
                int row = quad * 4 + r;
                float val = fmaxf(c[r], 0.f) + bf2f(hbf[(size_t)(r0 + row) * 128 + col]);
                hr_s[row][col] = (ushort_t)f2bf(val);
            }
        }
    }
    __syncthreads();
    // phase B (wave 0): logits^T = Wout . hr^T ; in-lane log_softmax per row
    if (w == 0) {
        f32x4 c[3];
#pragma unroll
        for (int mt = 0; mt < 3; ++mt)
#pragma unroll
            for (int r = 0; r < 4; ++r) {
                int oc = mt * 16 + quad * 4 + r;
                c[mt][r] = (oc < OUTC) ? bout[oc] : 0.f;
            }
#pragma unroll
        for (int kf = 0; kf < 4; ++kf) {
            bf16x8 bfrag = *(const bf16x8*)&hr_s[l15][kf * 32 + quad * 8];
#pragma unroll
            for (int mt = 0; mt < 3; ++mt) {
                bf16x8 afr = *(const bf16x8*)(woutfr + (((size_t)mt * 4 + kf) * 4 + quad) * 128 + l15 * 8);
                c[mt] = __builtin_amdgcn_mfma_f32_16x16x32_bf16(afr, bfrag, c[mt], 0, 0, 0);
            }
        }
        float mx = -1e30f;
#pragma unroll
        for (int mt = 0; mt < 3; ++mt)
#pragma unroll
            for (int r = 0; r < 4; ++r) {
                int oc = mt * 16 + quad * 4 + r;
                if (oc >= OUTC) c[mt][r] = -1e30f;
                mx = fmaxf(mx, c[mt][r]);
            }
        mx = fmaxf(mx, __shfl_xor(mx, 16, 64));
        mx = fmaxf(mx, __shfl_xor(mx, 32, 64));
        float ssum = 0.f;
#pragma unroll
        for (int mt = 0; mt < 3; ++mt)
#pragma unroll
            for (int r = 0; r < 4; ++r) ssum += __expf(c[mt][r] - mx);
        ssum += __shfl_xor(ssum, 16, 64);
        ssum += __shfl_xor(ssum, 32, 64);
        float lse = __logf(ssum) + mx;
        int row = r0 + l15;
#pragma unroll
        for (int mt = 0; mt < 2; ++mt) {
            float4 st = make_float4(c[mt][0] - lse, c[mt][1] - lse, c[mt][2] - lse, c[mt][3] - lse);
            *(float4*)(out + (size_t)row * OUTC + mt * 16 + quad * 4) = st;
        }
        if (quad < 2) {
            float4 st = make_float4(c[2][0] - lse, c[2][1] - lse, c[2][2] - lse, c[2][3] - lse);
            *(float4*)(out + (size_t)row * OUTC + 32 + quad * 4) = st;
        }
    }
}

extern "C" void kernel_launch(void* const* d_in, const int* in_sizes, int n_in,
                              void* d_out, int out_size, void* d_ws, size_t ws_size,
                              hipStream_t stream) {
    const float* x          = (const float*)d_in[0];
    // d_in[1] = pos_enc (unused in forward, faithful to reference)
    const float* sp         = (const float*)d_in[2];
    const float* W_in       = (const float*)d_in[3];
    const float* b_in       = (const float*)d_in[4];
    const float* in_proj_w  = (const float*)d_in[5];
    const float* in_proj_b  = (const float*)d_in[6];
    const float* out_proj_w = (const float*)d_in[7];
    const float* out_proj_b = (const float*)d_in[8];
    const float* W_out      = (const float*)d_in[9];
    const float* b_out      = (const float*)d_in[10];
    const float* scale      = (const float*)d_in[11];

    float*    pml    = (float*)d_ws;                          // 8192*4*2 f32 = 256 KiB
    ushort_t* pob    = (ushort_t*)(pml + (size_t)NROWS * 8);  // 4 MiB bf16 partial O
    ushort_t* xfr    = pob + (size_t)NROWS * 256;
    ushort_t* qfr    = xfr + (size_t)NROWS * 128;
    ushort_t* kfr    = qfr + (size_t)NROWS * 128;
    ushort_t* vfr    = kfr + (size_t)NROWS * 128;
    ushort_t* hbf    = vfr + (size_t)NROWS * 128;
    ushort_t* wifr   = hbf + (size_t)NROWS * 128;
    ushort_t* wpfr   = wifr + 128 * 128;
    ushort_t* wofr   = wpfr + 384 * 128;
    ushort_t* woutfr = wofr + 128 * 128;                      // 48*128 (zero-padded)
    float*    out    = (float*)d_out;

    hipLaunchKernelGGL(k_prep, dim3(555), dim3(256), 0, stream,
                       x, W_in, in_proj_w, out_proj_w, W_out, xfr, wifr, wpfr, wofr, woutfr);
    hipLaunchKernelGGL(k_qkv_fused, dim3(NROWS / 16), dim3(256), 0, stream,
                       xfr, wifr, b_in, wpfr, in_proj_b, hbf, qfr, kfr, vfr);
    hipLaunchKernelGGL(k_attn, dim3(256 * 2), dim3(256), 0, stream,
                       qfr, kfr, vfr, sp, scale, pob, pml);
    hipLaunchKernelGGL(k_epi, dim3(NROWS / 16), dim3(256), 0, stream,
                       hbf, pob, pml, wofr, out_proj_b, woutfr, b_out, out);
}